// Round 1
// 1137.708 us; speedup vs baseline: 1.0353x; 1.0353x over previous
//
#include <hip/hip_runtime.h>
#include <hip/hip_fp16.h>

#define D 128
#define KPASS 4
#define CAP1 80  // d1, d2 buckets (mean degree 32)
#define CAP2 56  // d12, s1, s2 buckets (mean degree 16)

// ===========================================================================
// ELL fill job descriptors (passed by value)
// Weighted payloads packed into one int: (idx << 15) | round(w * 32768).
// idx < 2^17 (N0 = 100000), w in [0,1) -> 15-bit fixed point, err <= 1.5e-5
// (negligible vs fp16 row storage err ~5e-4).
// ===========================================================================
struct FillJob {
    const int* key;    // bucket node id per edge
    const int* other;  // payload index per edge
    const float* w;    // weight (nullptr -> raw index payload)
    int* pay;          // payload at key*cap + slot
    int cbase;         // node base in concatenated cursor space
    int cap;           // bucket capacity
    int E, N;
};
struct FillJobs5 { FillJob j[5]; };

// ===========================================================================
// Windowed ELL fill pass k: edges with key in [N*k/K, N*(k+1)/K) only.
// Cursor atomic doubles as the degree histogram (read later by agg kernels).
// 4B payloads -> combined active windows ~2.8MB/XCD share, L2-resident.
// ===========================================================================
__global__ __launch_bounds__(256) void fill_pass_kernel(FillJobs5 J, int k,
                                                        int* __restrict__ cursor) {
    FillJob jb = J.j[blockIdx.y];
    int lo = (int)((long)jb.N * k / KPASS);
    int hi = (int)((long)jb.N * (k + 1) / KPASS);
    bool hasw = (jb.w != nullptr);
    for (long e = (long)blockIdx.x * 256 + threadIdx.x; e < jb.E;
         e += (long)gridDim.x * 256) {
        int key = jb.key[e];
        if (key < lo || key >= hi) continue;
        int pos = atomicAdd(&cursor[jb.cbase + key], 1);
        if (pos >= jb.cap) continue;  // overflow guard (prob ~1e-7 total)
        int o = jb.other[e];
        int v;
        if (hasw) {
            int w15 = __float2int_rn(jb.w[e] * 32768.0f);
            w15 = w15 > 32767 ? 32767 : w15;
            v = (int)(((unsigned)o << 15) | (unsigned)w15);
        } else {
            v = o;
        }
        jb.pay[(long)key * jb.cap + pos] = v;
    }
}

// ===========================================================================
// fp32 -> fp16 conversion (x_node table)
// ===========================================================================
__global__ void f2h_kernel(const float2* __restrict__ in, __half2* __restrict__ o,
                           long n2) {
    long i = (long)blockIdx.x * blockDim.x + threadIdx.x;
    if (i < n2) o[i] = __float22half2_rn(in[i]);
}

// ===========================================================================
// Wide-gather aggregation: 16B/lane float4 loads. A 256B fp16 row is covered
// by 16 lanes; the wave is split into 4 groups of 16 lanes, each group
// handling a different edge per iteration (1 load instr = 4 edges).
// Cross-group partial sums reduced with shfl_xor(16/32) at the end.
// ===========================================================================
__device__ __forceinline__ void acc8(float4 raw, float mul, float2 a[4]) {
    const __half2* h = (const __half2*)&raw;
#pragma unroll
    for (int k = 0; k < 4; ++k) {
        float2 f = __half22float2(h[k]);
        a[k].x = fmaf(f.x, mul, a[k].x);
        a[k].y = fmaf(f.y, mul, a[k].y);
    }
}

// Stage-1: gather fp16 rows, fp32 accumulate, combine with fp32 xb,
// write fp16 row at dst[node*dstride + doff]. One wave per node.
template <bool HASW>
__global__ __launch_bounds__(256) void aggh_kernel(
    const __half* __restrict__ vals, int vstride, const int* __restrict__ cnt,
    int cap, const int* __restrict__ pay, const float* __restrict__ xb,
    __half* __restrict__ dst, int dstride, int doff, int N) {
    int node = (int)(((long)blockIdx.x * 256 + threadIdx.x) >> 6);
    int lane = threadIdx.x & 63;
    if (node >= N) return;
    int count = cnt[node];
    int m = count < cap ? count : cap;
    long b0 = (long)node * cap;
    int grp = lane >> 4, il = lane & 15;
    float2 a[4] = {{0.f, 0.f}, {0.f, 0.f}, {0.f, 0.f}, {0.f, 0.f}};
    for (int base = 0; base < m; base += 64) {
        int rem = m - base;
        int n = rem < 64 ? rem : 64;
        int p = 0;
        if (lane < n) p = pay[b0 + base + lane];
        for (int j = 0; j < n; j += 4) {
            int jj = j + grp;  // j%4==0, grp<=3, j<=n-1 -> jj<=63
            int pj = __shfl(p, jj, 64);
            int g;
            float wt;
            if (HASW) {
                g = (int)(((unsigned)pj) >> 15);
                wt = (float)(pj & 0x7fff) * (1.0f / 32768.0f);
            } else {
                g = pj;
                wt = 1.0f;
            }
            float mul = jj < n ? wt : 0.0f;  // inactive -> row 0 loaded, x0
            float4 raw = ((const float4*)(vals + (long)g * vstride))[il];
            acc8(raw, mul, a);
        }
    }
#pragma unroll
    for (int k = 0; k < 4; ++k) {
        a[k].x += __shfl_xor(a[k].x, 16, 64);
        a[k].y += __shfl_xor(a[k].y, 16, 64);
        a[k].x += __shfl_xor(a[k].x, 32, 64);
        a[k].y += __shfl_xor(a[k].y, 32, 64);
    }
    if (lane < 16) {
        float inv = 1.0f / fmaxf((float)count, 1.0f);
        const float4* xp = (const float4*)(xb + (long)node * D + il * 8);
        float4 x0 = xp[0], x1 = xp[1];
        float rx[8] = {x0.x, x0.y, x0.z, x0.w, x1.x, x1.y, x1.z, x1.w};
        __half2 h[4];
#pragma unroll
        for (int k = 0; k < 4; ++k) {
            float2 r;
            r.x = (a[k].x * inv + rx[2 * k + 0]) * 0.5f;
            r.y = (a[k].y * inv + rx[2 * k + 1]) * 0.5f;
            h[k] = __float22half2_rn(r);
        }
        *(float4*)(dst + (long)node * dstride + doff + il * 8) = *(float4*)h;
    }
}

// Stage-2: pre1 = mean over fp16 net1h rows, fp32 output, no combine.
__global__ __launch_bounds__(256) void aggf_kernel(
    const __half* __restrict__ vals, const int* __restrict__ cnt, int cap,
    const int* __restrict__ pay, float* __restrict__ out, int N) {
    int node = (int)(((long)blockIdx.x * 256 + threadIdx.x) >> 6);
    int lane = threadIdx.x & 63;
    if (node >= N) return;
    int count = cnt[node];
    int m = count < cap ? count : cap;
    long b0 = (long)node * cap;
    int grp = lane >> 4, il = lane & 15;
    float2 a[4] = {{0.f, 0.f}, {0.f, 0.f}, {0.f, 0.f}, {0.f, 0.f}};
    for (int base = 0; base < m; base += 64) {
        int rem = m - base;
        int n = rem < 64 ? rem : 64;
        int p = 0;
        if (lane < n) p = pay[b0 + base + lane];
        for (int j = 0; j < n; j += 4) {
            int jj = j + grp;
            int pj = __shfl(p, jj, 64);
            float mul = jj < n ? 1.0f : 0.0f;
            float4 raw = ((const float4*)(vals + (long)pj * D))[il];
            acc8(raw, mul, a);
        }
    }
#pragma unroll
    for (int k = 0; k < 4; ++k) {
        a[k].x += __shfl_xor(a[k].x, 16, 64);
        a[k].y += __shfl_xor(a[k].y, 16, 64);
        a[k].x += __shfl_xor(a[k].x, 32, 64);
        a[k].y += __shfl_xor(a[k].y, 32, 64);
    }
    if (lane < 16) {
        float inv = 1.0f / fmaxf((float)count, 1.0f);
        float4* op = (float4*)(out + (long)node * D + il * 8);
        float4 o0 = {a[0].x * inv, a[0].y * inv, a[1].x * inv, a[1].y * inv};
        float4 o1 = {a[2].x * inv, a[2].y * inv, a[3].x * inv, a[3].y * inv};
        op[0] = o0;
        op[1] = o1;
    }
}

// Fused pre2/pre3: combo rows hold [net2h | net2bh] (256 halves, 512B).
// 32 lanes cover one row (il<16 -> a-half unweighted, il>=16 -> b-half
// weighted); 2 groups of 32 lanes = 2 edges per wave-load.
// Requires cap <= 64 (cap = CAP2 = 56): single payload batch.
__global__ __launch_bounds__(256) void agg2_kernel(
    const __half* __restrict__ combo, const int* __restrict__ cnt, int cap,
    const int* __restrict__ pay, float* __restrict__ outa,
    float* __restrict__ outb, int N) {
    int node = (int)(((long)blockIdx.x * 256 + threadIdx.x) >> 6);
    int lane = threadIdx.x & 63;
    if (node >= N) return;
    int count = cnt[node];
    int m = count < cap ? count : cap;
    long b0 = (long)node * cap;
    int grp = lane >> 5, il = lane & 31;
    float2 a[4] = {{0.f, 0.f}, {0.f, 0.f}, {0.f, 0.f}, {0.f, 0.f}};
    int p = 0;
    if (lane < m) p = pay[b0 + lane];
    for (int j = 0; j < m; j += 2) {
        int jj = j + grp;
        int pj = __shfl(p, jj, 64);
        int g = (int)(((unsigned)pj) >> 15);
        float w = (float)(pj & 0x7fff) * (1.0f / 32768.0f);
        float mul = jj < m ? (il < 16 ? 1.0f : w) : 0.0f;
        float4 raw = ((const float4*)(combo + (long)g * 256))[il];
        acc8(raw, mul, a);
    }
#pragma unroll
    for (int k = 0; k < 4; ++k) {
        a[k].x += __shfl_xor(a[k].x, 32, 64);
        a[k].y += __shfl_xor(a[k].y, 32, 64);
    }
    if (lane < 32) {
        float inv = 1.0f / fmaxf((float)count, 1.0f);
        float* o = (il < 16) ? (outa + (long)node * D + il * 8)
                             : (outb + (long)node * D + (il - 16) * 8);
        float4 o0 = {a[0].x * inv, a[0].y * inv, a[1].x * inv, a[1].y * inv};
        float4 o1 = {a[2].x * inv, a[2].y * inv, a[3].x * inv, a[3].y * inv};
        ((float4*)o)[0] = o0;
        ((float4*)o)[1] = o1;
    }
}

// ===========================================================================
// post = relu(pre @ W^T + b), in place on pre.
// ===========================================================================
__global__ __launch_bounds__(256) void linrelu_kernel(
    float* __restrict__ pre, const float* __restrict__ W,
    const float* __restrict__ bias, int N) {
    __shared__ __align__(16) float Wt[64 * D];
    __shared__ __align__(16) float At[64 * 32];
    int tid = threadIdx.x;
    int m0 = blockIdx.x * 32;
    int tn = (tid & 15) * 8;
    int tm = (tid >> 4) * 2;

    float acc[2][8];
#pragma unroll
    for (int i = 0; i < 2; ++i)
#pragma unroll
        for (int j = 0; j < 8; ++j) acc[i][j] = 0.0f;

    for (int kk = 0; kk < 2; ++kk) {
        int kbase = kk * 64;
#pragma unroll
        for (int j = 0; j < 8; ++j) {
            int idx4 = tid + j * 256;
            int n = idx4 & 127;
            int kloc = (idx4 >> 7) * 4;
            float4 v = *(const float4*)(W + (long)n * D + kbase + kloc);
            Wt[(kloc + 0) * D + n] = v.x;
            Wt[(kloc + 1) * D + n] = v.y;
            Wt[(kloc + 2) * D + n] = v.z;
            Wt[(kloc + 3) * D + n] = v.w;
        }
#pragma unroll
        for (int j = 0; j < 2; ++j) {
            int idx4 = tid + j * 256;
            int m = idx4 & 31;
            int kloc = (idx4 >> 5) * 4;
            float4 v = {0.0f, 0.0f, 0.0f, 0.0f};
            if (m0 + m < N) v = *(const float4*)(pre + (long)(m0 + m) * D + kbase + kloc);
            At[(kloc + 0) * 32 + m] = v.x;
            At[(kloc + 1) * 32 + m] = v.y;
            At[(kloc + 2) * 32 + m] = v.z;
            At[(kloc + 3) * 32 + m] = v.w;
        }
        __syncthreads();
#pragma unroll
        for (int kloc = 0; kloc < 64; ++kloc) {
            float a0 = At[kloc * 32 + tm];
            float a1 = At[kloc * 32 + tm + 1];
            float4 b0 = *(const float4*)&Wt[kloc * D + tn];
            float4 b1 = *(const float4*)&Wt[kloc * D + tn + 4];
            acc[0][0] += a0 * b0.x; acc[0][1] += a0 * b0.y;
            acc[0][2] += a0 * b0.z; acc[0][3] += a0 * b0.w;
            acc[0][4] += a0 * b1.x; acc[0][5] += a0 * b1.y;
            acc[0][6] += a0 * b1.z; acc[0][7] += a0 * b1.w;
            acc[1][0] += a1 * b0.x; acc[1][1] += a1 * b0.y;
            acc[1][2] += a1 * b0.z; acc[1][3] += a1 * b0.w;
            acc[1][4] += a1 * b1.x; acc[1][5] += a1 * b1.y;
            acc[1][6] += a1 * b1.z; acc[1][7] += a1 * b1.w;
        }
        __syncthreads();
    }
    float4 bv0 = *(const float4*)(bias + tn);
    float4 bv1 = *(const float4*)(bias + tn + 4);
#pragma unroll
    for (int i = 0; i < 2; ++i) {
        int node = m0 + tm + i;
        if (node >= N) continue;
        float4 o0, o1;
        o0.x = fmaxf(acc[i][0] + bv0.x, 0.0f);
        o0.y = fmaxf(acc[i][1] + bv0.y, 0.0f);
        o0.z = fmaxf(acc[i][2] + bv0.z, 0.0f);
        o0.w = fmaxf(acc[i][3] + bv0.w, 0.0f);
        o1.x = fmaxf(acc[i][4] + bv1.x, 0.0f);
        o1.y = fmaxf(acc[i][5] + bv1.y, 0.0f);
        o1.z = fmaxf(acc[i][6] + bv1.z, 0.0f);
        o1.w = fmaxf(acc[i][7] + bv1.w, 0.0f);
        *(float4*)(pre + (long)node * D + tn) = o0;
        *(float4*)(pre + (long)node * D + tn + 4) = o1;
    }
}

// ===========================================================================
// Attention; one wave per node. p3 may alias out (read-before-write).
// ===========================================================================
__global__ __launch_bounds__(256) void attn_kernel(
    const float* __restrict__ p1, const float* __restrict__ p2,
    const float* __restrict__ p3, const float* __restrict__ att,
    float* __restrict__ out, int N) {
    int gw = (int)(((long)blockIdx.x * 256 + threadIdx.x) >> 6);
    int lane = threadIdx.x & 63;
    if (gw >= N) return;
    long base = (long)gw * D + lane * 2;
    float2 v1 = *(const float2*)(p1 + base);
    float2 v2 = *(const float2*)(p2 + base);
    float2 v3 = *(const float2*)(p3 + base);
    float2 a1 = *(const float2*)(att + 0 * D + lane * 2);
    float2 a2 = *(const float2*)(att + 1 * D + lane * 2);
    float2 a3 = *(const float2*)(att + 2 * D + lane * 2);
    float s1 = v1.x * a1.x + v1.y * a1.y;
    float s2 = v2.x * a2.x + v2.y * a2.y;
    float s3 = v3.x * a3.x + v3.y * a3.y;
#pragma unroll
    for (int off = 32; off > 0; off >>= 1) {
        s1 += __shfl_xor(s1, off, 64);
        s2 += __shfl_xor(s2, off, 64);
        s3 += __shfl_xor(s3, off, 64);
    }
    float m = fmaxf(s1, fmaxf(s2, s3));
    float e1 = __expf(s1 - m), e2 = __expf(s2 - m), e3 = __expf(s3 - m);
    float inv = 1.0f / (e1 + e2 + e3);
    float w1 = e1 * inv, w2 = e2 * inv, w3 = e3 * inv;
    float2 o;
    o.x = v1.x * w1 + v2.x * w2 + v3.x * w3;
    o.y = v1.y * w1 + v2.y * w2 + v3.y * w3;
    *(float2*)(out + base) = o;
}

// ===========================================================================
extern "C" void kernel_launch(void* const* d_in, const int* in_sizes, int n_in,
                              void* d_out, int out_size, void* d_ws,
                              size_t ws_size, hipStream_t stream) {
    const float* x_node = (const float*)d_in[0];
    const float* x1 = (const float*)d_in[1];
    const float* x2 = (const float*)d_in[2];
    const int* ei1_src = (const int*)d_in[3];
    const int* ei1_dst = (const int*)d_in[4];
    const int* ei2_src = (const int*)d_in[5];
    const int* ei2_dst = (const int*)d_in[6];
    const int* ei12_src = (const int*)d_in[7];
    const int* ei12_dst = (const int*)d_in[8];
    const float* ew1 = (const float*)d_in[9];
    const float* ew2 = (const float*)d_in[10];
    const float* W1 = (const float*)d_in[11];
    const float* b1 = (const float*)d_in[12];
    const float* W2 = (const float*)d_in[13];
    const float* b2 = (const float*)d_in[14];
    const float* W12 = (const float*)d_in[15];
    const float* b12 = (const float*)d_in[16];
    const float* att = (const float*)d_in[17];
    float* out = (float*)d_out;

    const int N0 = in_sizes[0] / D;
    const int N1 = in_sizes[1] / D;
    const int N2 = in_sizes[2] / D;
    const int E1 = in_sizes[3];
    const int E2 = in_sizes[5];
    const int E12 = in_sizes[7];

    float* ws = (float*)d_ws;
    size_t off = 0;
    auto A = [](size_t v) { return (v + 3) & ~(size_t)3; };  // 16B align (words)

    // fp16 tables
    __half* xh = (__half*)(ws + off);    off += A((size_t)N0 * D / 2);
    __half* net1h = (__half*)(ws + off); off += A((size_t)N1 * D / 2);
    __half* combo = (__half*)(ws + off); off += A((size_t)N2 * D);  // 256 h/row

    // --- ELL payload block A: pay_d12, pay_s1 (dead after aggf) ---
    // pre2 aliases this block (written by agg2, after both are dead).
    size_t pA = off;
    int* pay_d12 = (int*)(ws + off); off += A((size_t)N2 * CAP2);
    int* pay_s1 = (int*)(ws + off);  off += A((size_t)N0 * CAP2);
    size_t needA = pA + (size_t)N0 * D;  // pre2 words
    if (off < needA) off = needA;
    float* pre2 = ws + pA;

    // --- ELL payload block B: pay_d1, pay_d2 (dead after aggh d1/d2) ---
    // pre1 aliases this block (written by aggf, after both are dead).
    size_t pB = off;
    int* pay_d1 = (int*)(ws + off); off += A((size_t)N1 * CAP1);
    int* pay_d2 = (int*)(ws + off); off += A((size_t)N2 * CAP1);
    size_t needB = pB + (size_t)N0 * D;  // pre1 words
    if (off < needB) off = needB;
    float* pre1 = ws + pB;

    int* pay_s2 = (int*)(ws + off); off += A((size_t)N0 * CAP2);
    float* pre3 = out;  // d_out doubles as pre3 scratch

    // concatenated cursors [d1:N1][d2:N2][d12:N2][s1:N0][s2:N0] (zeroed)
    const int NT = N1 + 2 * N2 + 2 * N0;
    int* cur = (int*)(ws + off); off += A(NT);
    const int cb_d1 = 0, cb_d2 = N1, cb_d12 = N1 + N2;
    const int cb_s1 = N1 + 2 * N2, cb_s2 = N1 + 2 * N2 + N0;

    hipMemsetAsync((void*)cur, 0, (size_t)NT * sizeof(int), stream);

    // x_node -> fp16
    long n2 = (long)N0 * D / 2;
    f2h_kernel<<<(n2 + 255) / 256, 256, 0, stream>>>((const float2*)x_node,
                                                     (__half2*)xh, n2);

    // windowed ELL fills (cursor atomic doubles as histogram; no scan)
    FillJobs5 F;
    F.j[0] = {ei1_dst, ei1_src, ew1, pay_d1, cb_d1, CAP1, E1, N1};
    F.j[1] = {ei2_dst, ei2_src, ew2, pay_d2, cb_d2, CAP1, E2, N2};
    F.j[2] = {ei12_dst, ei12_src, nullptr, pay_d12, cb_d12, CAP2, E12, N2};
    F.j[3] = {ei1_src, ei1_dst, nullptr, pay_s1, cb_s1, CAP2, E1, N0};
    F.j[4] = {ei2_src, ei2_dst, ew2, pay_s2, cb_s2, CAP2, E2, N0};
    for (int k = 0; k < KPASS; ++k)
        fill_pass_kernel<<<dim3(2048, 5), 256, 0, stream>>>(F, k, cur);

    // aggregations
    auto blocks = [](int n) { return (n + 3) / 4; };
    aggh_kernel<true><<<blocks(N1), 256, 0, stream>>>(
        xh, D, cur + cb_d1, CAP1, pay_d1, x1, net1h, D, 0, N1);
    aggh_kernel<true><<<blocks(N2), 256, 0, stream>>>(
        xh, D, cur + cb_d2, CAP1, pay_d2, x2, combo, 2 * D, 0, N2);
    aggh_kernel<false><<<blocks(N2), 256, 0, stream>>>(
        net1h, D, cur + cb_d12, CAP2, pay_d12, x2, combo, 2 * D, D, N2);
    aggf_kernel<<<blocks(N0), 256, 0, stream>>>(net1h, cur + cb_s1, CAP2,
                                                pay_s1, pre1, N0);
    agg2_kernel<<<blocks(N0), 256, 0, stream>>>(combo, cur + cb_s2, CAP2,
                                                pay_s2, pre2, pre3, N0);

    // linear + relu (in place)
    const int gb = (N0 + 31) / 32;
    linrelu_kernel<<<gb, 256, 0, stream>>>(pre1, W1, b1, N0);
    linrelu_kernel<<<gb, 256, 0, stream>>>(pre2, W2, b2, N0);
    linrelu_kernel<<<gb, 256, 0, stream>>>(pre3, W12, b12, N0);

    // attention combine (p3 aliases out)
    attn_kernel<<<(N0 + 3) / 4, 256, 0, stream>>>(pre1, pre2, pre3, att, out, N0);
}

// Round 2
// 1126.064 us; speedup vs baseline: 1.0460x; 1.0103x over previous
//
#include <hip/hip_runtime.h>
#include <hip/hip_fp16.h>

#define D 128
#define KPASS 4
#define CAP1 80  // d1, d2 buckets (mean degree 32)
#define CAP2 56  // d12, s1, s2 buckets (mean degree 16)

// ===========================================================================
// ELL fill job descriptors (passed by value)
// Weighted payloads packed into one int: (idx << 15) | round(w * 32768).
// idx < 2^17 (N0 = 100000), w in [0,1) -> 15-bit fixed point, err <= 1.5e-5
// (negligible vs fp16 row storage err ~5e-4).
// ===========================================================================
struct FillJob {
    const int* key;    // bucket node id per edge
    const int* other;  // payload index per edge
    const float* w;    // weight (nullptr -> raw index payload)
    int* pay;          // payload at key*cap + slot
    int cbase;         // node base in concatenated cursor space
    int cap;           // bucket capacity
    int E, N;
};
struct FillJobs5 { FillJob j[5]; };

// ===========================================================================
// Windowed ELL fill pass k: edges with key in [N*k/K, N*(k+1)/K) only.
// Cursor atomic doubles as the degree histogram (read later by agg kernels).
// ===========================================================================
__global__ __launch_bounds__(256) void fill_pass_kernel(FillJobs5 J, int k,
                                                        int* __restrict__ cursor) {
    FillJob jb = J.j[blockIdx.y];
    int lo = (int)((long)jb.N * k / KPASS);
    int hi = (int)((long)jb.N * (k + 1) / KPASS);
    bool hasw = (jb.w != nullptr);
    for (long e = (long)blockIdx.x * 256 + threadIdx.x; e < jb.E;
         e += (long)gridDim.x * 256) {
        int key = jb.key[e];
        if (key < lo || key >= hi) continue;
        int pos = atomicAdd(&cursor[jb.cbase + key], 1);
        if (pos >= jb.cap) continue;  // overflow guard (prob ~1e-7 total)
        int o = jb.other[e];
        int v;
        if (hasw) {
            int w15 = __float2int_rn(jb.w[e] * 32768.0f);
            w15 = w15 > 32767 ? 32767 : w15;
            v = (int)(((unsigned)o << 15) | (unsigned)w15);
        } else {
            v = o;
        }
        jb.pay[(long)key * jb.cap + pos] = v;
    }
}

// ===========================================================================
// fp32 -> fp16 conversion (x_node table)
// ===========================================================================
__global__ void f2h_kernel(const float2* __restrict__ in, __half2* __restrict__ o,
                           long n2) {
    long i = (long)blockIdx.x * blockDim.x + threadIdx.x;
    if (i < n2) o[i] = __float22half2_rn(in[i]);
}

// ===========================================================================
// Wide-gather aggregation, 16B/lane float4 loads, 4-deep unrolled so four
// independent gathers are in flight per wave (latency hiding; Little's law:
// 1 load in flight capped request BW at ~7.2 TB/s in R1 measurements).
// A 256B fp16 row is covered by 16 lanes (4 groups/wave = 4 edges per load
// instr); inactive tail slots gather row 0 (L1-hot) with weight 0.
// ===========================================================================
__device__ __forceinline__ void acc8(float4 raw, float mul, float2 a[4]) {
    const __half2* h = (const __half2*)&raw;
#pragma unroll
    for (int k = 0; k < 4; ++k) {
        float2 f = __half22float2(h[k]);
        a[k].x = fmaf(f.x, mul, a[k].x);
        a[k].y = fmaf(f.y, mul, a[k].y);
    }
}

template <bool HASW>
__device__ __forceinline__ void decode_pw(int pj, int& g, float& w) {
    if (HASW) {
        g = (int)(((unsigned)pj) >> 15);
        w = (float)(pj & 0x7fff) * (1.0f / 32768.0f);
    } else {
        g = pj;
        w = 1.0f;
    }
}

// Stage-1: gather fp16 rows, fp32 accumulate, combine with fp32 xb,
// write fp16 row at dst[node*dstride + doff]. One wave per node.
template <bool HASW>
__global__ __launch_bounds__(256) void aggh_kernel(
    const __half* __restrict__ vals, int vstride, const int* __restrict__ cnt,
    int cap, const int* __restrict__ pay, const float* __restrict__ xb,
    __half* __restrict__ dst, int dstride, int doff, int N) {
    int node = (int)(((long)blockIdx.x * 256 + threadIdx.x) >> 6);
    int lane = threadIdx.x & 63;
    if (node >= N) return;
    int count = cnt[node];
    int m = count < cap ? count : cap;
    long b0 = (long)node * cap;
    int grp = lane >> 4, il = lane & 15;
    float2 a[4] = {{0.f, 0.f}, {0.f, 0.f}, {0.f, 0.f}, {0.f, 0.f}};
    for (int base = 0; base < m; base += 64) {
        int rem = m - base;
        int n = rem < 64 ? rem : 64;
        int p = 0;
        if (lane < n) p = pay[b0 + base + lane];
        for (int j = 0; j < n; j += 16) {
            int jj0 = j + grp, jj1 = j + 4 + grp, jj2 = j + 8 + grp,
                jj3 = j + 12 + grp;
            int p0 = __shfl(p, jj0, 64), p1 = __shfl(p, jj1, 64);
            int p2 = __shfl(p, jj2, 64), p3 = __shfl(p, jj3, 64);
            int g0, g1, g2, g3;
            float w0, w1, w2, w3;
            decode_pw<HASW>(p0, g0, w0);
            decode_pw<HASW>(p1, g1, w1);
            decode_pw<HASW>(p2, g2, w2);
            decode_pw<HASW>(p3, g3, w3);
            float m0 = jj0 < n ? w0 : 0.0f;
            float m1 = jj1 < n ? w1 : 0.0f;
            float m2 = jj2 < n ? w2 : 0.0f;
            float m3 = jj3 < n ? w3 : 0.0f;
            // four independent gathers issued before any accumulate
            float4 r0 = ((const float4*)(vals + (long)g0 * vstride))[il];
            float4 r1 = ((const float4*)(vals + (long)g1 * vstride))[il];
            float4 r2 = ((const float4*)(vals + (long)g2 * vstride))[il];
            float4 r3 = ((const float4*)(vals + (long)g3 * vstride))[il];
            acc8(r0, m0, a);
            acc8(r1, m1, a);
            acc8(r2, m2, a);
            acc8(r3, m3, a);
        }
    }
#pragma unroll
    for (int k = 0; k < 4; ++k) {
        a[k].x += __shfl_xor(a[k].x, 16, 64);
        a[k].y += __shfl_xor(a[k].y, 16, 64);
        a[k].x += __shfl_xor(a[k].x, 32, 64);
        a[k].y += __shfl_xor(a[k].y, 32, 64);
    }
    if (lane < 16) {
        float inv = 1.0f / fmaxf((float)count, 1.0f);
        const float4* xp = (const float4*)(xb + (long)node * D + il * 8);
        float4 x0 = xp[0], x1 = xp[1];
        float rx[8] = {x0.x, x0.y, x0.z, x0.w, x1.x, x1.y, x1.z, x1.w};
        __half2 h[4];
#pragma unroll
        for (int k = 0; k < 4; ++k) {
            float2 r;
            r.x = (a[k].x * inv + rx[2 * k + 0]) * 0.5f;
            r.y = (a[k].y * inv + rx[2 * k + 1]) * 0.5f;
            h[k] = __float22half2_rn(r);
        }
        *(float4*)(dst + (long)node * dstride + doff + il * 8) = *(float4*)h;
    }
}

// Stage-2: pre1 = mean over fp16 net1h rows, fp32 output, no combine.
__global__ __launch_bounds__(256) void aggf_kernel(
    const __half* __restrict__ vals, const int* __restrict__ cnt, int cap,
    const int* __restrict__ pay, float* __restrict__ out, int N) {
    int node = (int)(((long)blockIdx.x * 256 + threadIdx.x) >> 6);
    int lane = threadIdx.x & 63;
    if (node >= N) return;
    int count = cnt[node];
    int m = count < cap ? count : cap;
    long b0 = (long)node * cap;
    int grp = lane >> 4, il = lane & 15;
    float2 a[4] = {{0.f, 0.f}, {0.f, 0.f}, {0.f, 0.f}, {0.f, 0.f}};
    for (int base = 0; base < m; base += 64) {
        int rem = m - base;
        int n = rem < 64 ? rem : 64;
        int p = 0;
        if (lane < n) p = pay[b0 + base + lane];
        for (int j = 0; j < n; j += 16) {
            int jj0 = j + grp, jj1 = j + 4 + grp, jj2 = j + 8 + grp,
                jj3 = j + 12 + grp;
            int g0 = __shfl(p, jj0, 64), g1 = __shfl(p, jj1, 64);
            int g2 = __shfl(p, jj2, 64), g3 = __shfl(p, jj3, 64);
            float m0 = jj0 < n ? 1.0f : 0.0f;
            float m1 = jj1 < n ? 1.0f : 0.0f;
            float m2 = jj2 < n ? 1.0f : 0.0f;
            float m3 = jj3 < n ? 1.0f : 0.0f;
            float4 r0 = ((const float4*)(vals + (long)g0 * D))[il];
            float4 r1 = ((const float4*)(vals + (long)g1 * D))[il];
            float4 r2 = ((const float4*)(vals + (long)g2 * D))[il];
            float4 r3 = ((const float4*)(vals + (long)g3 * D))[il];
            acc8(r0, m0, a);
            acc8(r1, m1, a);
            acc8(r2, m2, a);
            acc8(r3, m3, a);
        }
    }
#pragma unroll
    for (int k = 0; k < 4; ++k) {
        a[k].x += __shfl_xor(a[k].x, 16, 64);
        a[k].y += __shfl_xor(a[k].y, 16, 64);
        a[k].x += __shfl_xor(a[k].x, 32, 64);
        a[k].y += __shfl_xor(a[k].y, 32, 64);
    }
    if (lane < 16) {
        float inv = 1.0f / fmaxf((float)count, 1.0f);
        float4* op = (float4*)(out + (long)node * D + il * 8);
        float4 o0 = {a[0].x * inv, a[0].y * inv, a[1].x * inv, a[1].y * inv};
        float4 o1 = {a[2].x * inv, a[2].y * inv, a[3].x * inv, a[3].y * inv};
        op[0] = o0;
        op[1] = o1;
    }
}

// Fused pre2/pre3: combo rows hold [net2h | net2bh] (256 halves, 512B).
// 32 lanes cover one row (il<16 -> a-half unweighted, il>=16 -> b-half
// weighted); 2 groups of 32 lanes; 4-deep unroll = 8 edges per iter.
// Requires cap <= 64 (cap = CAP2 = 56): single payload batch.
__global__ __launch_bounds__(256) void agg2_kernel(
    const __half* __restrict__ combo, const int* __restrict__ cnt, int cap,
    const int* __restrict__ pay, float* __restrict__ outa,
    float* __restrict__ outb, int N) {
    int node = (int)(((long)blockIdx.x * 256 + threadIdx.x) >> 6);
    int lane = threadIdx.x & 63;
    if (node >= N) return;
    int count = cnt[node];
    int m = count < cap ? count : cap;
    long b0 = (long)node * cap;
    int grp = lane >> 5, il = lane & 31;
    float2 a[4] = {{0.f, 0.f}, {0.f, 0.f}, {0.f, 0.f}, {0.f, 0.f}};
    int p = 0;
    if (lane < m) p = pay[b0 + lane];
    for (int j = 0; j < m; j += 8) {
        int jj0 = j + grp, jj1 = j + 2 + grp, jj2 = j + 4 + grp,
            jj3 = j + 6 + grp;
        int p0 = __shfl(p, jj0, 64), p1 = __shfl(p, jj1, 64);
        int p2 = __shfl(p, jj2, 64), p3 = __shfl(p, jj3, 64);
        int g0 = (int)(((unsigned)p0) >> 15), g1 = (int)(((unsigned)p1) >> 15);
        int g2 = (int)(((unsigned)p2) >> 15), g3 = (int)(((unsigned)p3) >> 15);
        float w0 = (float)(p0 & 0x7fff) * (1.0f / 32768.0f);
        float w1 = (float)(p1 & 0x7fff) * (1.0f / 32768.0f);
        float w2 = (float)(p2 & 0x7fff) * (1.0f / 32768.0f);
        float w3 = (float)(p3 & 0x7fff) * (1.0f / 32768.0f);
        float m0 = jj0 < m ? (il < 16 ? 1.0f : w0) : 0.0f;
        float m1 = jj1 < m ? (il < 16 ? 1.0f : w1) : 0.0f;
        float m2 = jj2 < m ? (il < 16 ? 1.0f : w2) : 0.0f;
        float m3 = jj3 < m ? (il < 16 ? 1.0f : w3) : 0.0f;
        float4 r0 = ((const float4*)(combo + (long)g0 * 256))[il];
        float4 r1 = ((const float4*)(combo + (long)g1 * 256))[il];
        float4 r2 = ((const float4*)(combo + (long)g2 * 256))[il];
        float4 r3 = ((const float4*)(combo + (long)g3 * 256))[il];
        acc8(r0, m0, a);
        acc8(r1, m1, a);
        acc8(r2, m2, a);
        acc8(r3, m3, a);
    }
#pragma unroll
    for (int k = 0; k < 4; ++k) {
        a[k].x += __shfl_xor(a[k].x, 32, 64);
        a[k].y += __shfl_xor(a[k].y, 32, 64);
    }
    if (lane < 32) {
        float inv = 1.0f / fmaxf((float)count, 1.0f);
        float* o = (il < 16) ? (outa + (long)node * D + il * 8)
                             : (outb + (long)node * D + (il - 16) * 8);
        float4 o0 = {a[0].x * inv, a[0].y * inv, a[1].x * inv, a[1].y * inv};
        float4 o1 = {a[2].x * inv, a[2].y * inv, a[3].x * inv, a[3].y * inv};
        ((float4*)o)[0] = o0;
        ((float4*)o)[1] = o1;
    }
}

// ===========================================================================
// post = relu(pre @ W^T + b), in place on pre.
// ===========================================================================
__global__ __launch_bounds__(256) void linrelu_kernel(
    float* __restrict__ pre, const float* __restrict__ W,
    const float* __restrict__ bias, int N) {
    __shared__ __align__(16) float Wt[64 * D];
    __shared__ __align__(16) float At[64 * 32];
    int tid = threadIdx.x;
    int m0 = blockIdx.x * 32;
    int tn = (tid & 15) * 8;
    int tm = (tid >> 4) * 2;

    float acc[2][8];
#pragma unroll
    for (int i = 0; i < 2; ++i)
#pragma unroll
        for (int j = 0; j < 8; ++j) acc[i][j] = 0.0f;

    for (int kk = 0; kk < 2; ++kk) {
        int kbase = kk * 64;
#pragma unroll
        for (int j = 0; j < 8; ++j) {
            int idx4 = tid + j * 256;
            int n = idx4 & 127;
            int kloc = (idx4 >> 7) * 4;
            float4 v = *(const float4*)(W + (long)n * D + kbase + kloc);
            Wt[(kloc + 0) * D + n] = v.x;
            Wt[(kloc + 1) * D + n] = v.y;
            Wt[(kloc + 2) * D + n] = v.z;
            Wt[(kloc + 3) * D + n] = v.w;
        }
#pragma unroll
        for (int j = 0; j < 2; ++j) {
            int idx4 = tid + j * 256;
            int m = idx4 & 31;
            int kloc = (idx4 >> 5) * 4;
            float4 v = {0.0f, 0.0f, 0.0f, 0.0f};
            if (m0 + m < N) v = *(const float4*)(pre + (long)(m0 + m) * D + kbase + kloc);
            At[(kloc + 0) * 32 + m] = v.x;
            At[(kloc + 1) * 32 + m] = v.y;
            At[(kloc + 2) * 32 + m] = v.z;
            At[(kloc + 3) * 32 + m] = v.w;
        }
        __syncthreads();
#pragma unroll
        for (int kloc = 0; kloc < 64; ++kloc) {
            float a0 = At[kloc * 32 + tm];
            float a1 = At[kloc * 32 + tm + 1];
            float4 b0 = *(const float4*)&Wt[kloc * D + tn];
            float4 b1 = *(const float4*)&Wt[kloc * D + tn + 4];
            acc[0][0] += a0 * b0.x; acc[0][1] += a0 * b0.y;
            acc[0][2] += a0 * b0.z; acc[0][3] += a0 * b0.w;
            acc[0][4] += a0 * b1.x; acc[0][5] += a0 * b1.y;
            acc[0][6] += a0 * b1.z; acc[0][7] += a0 * b1.w;
            acc[1][0] += a1 * b0.x; acc[1][1] += a1 * b0.y;
            acc[1][2] += a1 * b0.z; acc[1][3] += a1 * b0.w;
            acc[1][4] += a1 * b1.x; acc[1][5] += a1 * b1.y;
            acc[1][6] += a1 * b1.z; acc[1][7] += a1 * b1.w;
        }
        __syncthreads();
    }
    float4 bv0 = *(const float4*)(bias + tn);
    float4 bv1 = *(const float4*)(bias + tn + 4);
#pragma unroll
    for (int i = 0; i < 2; ++i) {
        int node = m0 + tm + i;
        if (node >= N) continue;
        float4 o0, o1;
        o0.x = fmaxf(acc[i][0] + bv0.x, 0.0f);
        o0.y = fmaxf(acc[i][1] + bv0.y, 0.0f);
        o0.z = fmaxf(acc[i][2] + bv0.z, 0.0f);
        o0.w = fmaxf(acc[i][3] + bv0.w, 0.0f);
        o1.x = fmaxf(acc[i][4] + bv1.x, 0.0f);
        o1.y = fmaxf(acc[i][5] + bv1.y, 0.0f);
        o1.z = fmaxf(acc[i][6] + bv1.z, 0.0f);
        o1.w = fmaxf(acc[i][7] + bv1.w, 0.0f);
        *(float4*)(pre + (long)node * D + tn) = o0;
        *(float4*)(pre + (long)node * D + tn + 4) = o1;
    }
}

// ===========================================================================
// Attention; one wave per node. p3 may alias out (read-before-write).
// ===========================================================================
__global__ __launch_bounds__(256) void attn_kernel(
    const float* __restrict__ p1, const float* __restrict__ p2,
    const float* __restrict__ p3, const float* __restrict__ att,
    float* __restrict__ out, int N) {
    int gw = (int)(((long)blockIdx.x * 256 + threadIdx.x) >> 6);
    int lane = threadIdx.x & 63;
    if (gw >= N) return;
    long base = (long)gw * D + lane * 2;
    float2 v1 = *(const float2*)(p1 + base);
    float2 v2 = *(const float2*)(p2 + base);
    float2 v3 = *(const float2*)(p3 + base);
    float2 a1 = *(const float2*)(att + 0 * D + lane * 2);
    float2 a2 = *(const float2*)(att + 1 * D + lane * 2);
    float2 a3 = *(const float2*)(att + 2 * D + lane * 2);
    float s1 = v1.x * a1.x + v1.y * a1.y;
    float s2 = v2.x * a2.x + v2.y * a2.y;
    float s3 = v3.x * a3.x + v3.y * a3.y;
#pragma unroll
    for (int off = 32; off > 0; off >>= 1) {
        s1 += __shfl_xor(s1, off, 64);
        s2 += __shfl_xor(s2, off, 64);
        s3 += __shfl_xor(s3, off, 64);
    }
    float m = fmaxf(s1, fmaxf(s2, s3));
    float e1 = __expf(s1 - m), e2 = __expf(s2 - m), e3 = __expf(s3 - m);
    float inv = 1.0f / (e1 + e2 + e3);
    float w1 = e1 * inv, w2 = e2 * inv, w3 = e3 * inv;
    float2 o;
    o.x = v1.x * w1 + v2.x * w2 + v3.x * w3;
    o.y = v1.y * w1 + v2.y * w2 + v3.y * w3;
    *(float2*)(out + base) = o;
}

// ===========================================================================
extern "C" void kernel_launch(void* const* d_in, const int* in_sizes, int n_in,
                              void* d_out, int out_size, void* d_ws,
                              size_t ws_size, hipStream_t stream) {
    const float* x_node = (const float*)d_in[0];
    const float* x1 = (const float*)d_in[1];
    const float* x2 = (const float*)d_in[2];
    const int* ei1_src = (const int*)d_in[3];
    const int* ei1_dst = (const int*)d_in[4];
    const int* ei2_src = (const int*)d_in[5];
    const int* ei2_dst = (const int*)d_in[6];
    const int* ei12_src = (const int*)d_in[7];
    const int* ei12_dst = (const int*)d_in[8];
    const float* ew1 = (const float*)d_in[9];
    const float* ew2 = (const float*)d_in[10];
    const float* W1 = (const float*)d_in[11];
    const float* b1 = (const float*)d_in[12];
    const float* W2 = (const float*)d_in[13];
    const float* b2 = (const float*)d_in[14];
    const float* W12 = (const float*)d_in[15];
    const float* b12 = (const float*)d_in[16];
    const float* att = (const float*)d_in[17];
    float* out = (float*)d_out;

    const int N0 = in_sizes[0] / D;
    const int N1 = in_sizes[1] / D;
    const int N2 = in_sizes[2] / D;
    const int E1 = in_sizes[3];
    const int E2 = in_sizes[5];
    const int E12 = in_sizes[7];

    float* ws = (float*)d_ws;
    size_t off = 0;
    auto A = [](size_t v) { return (v + 3) & ~(size_t)3; };  // 16B align (words)

    // fp16 tables
    __half* xh = (__half*)(ws + off);    off += A((size_t)N0 * D / 2);
    __half* net1h = (__half*)(ws + off); off += A((size_t)N1 * D / 2);
    __half* combo = (__half*)(ws + off); off += A((size_t)N2 * D);  // 256 h/row

    // --- ELL payload block A: pay_d12, pay_s1 (dead after aggf) ---
    // pre2 aliases this block (written by agg2, after both are dead).
    size_t pA = off;
    int* pay_d12 = (int*)(ws + off); off += A((size_t)N2 * CAP2);
    int* pay_s1 = (int*)(ws + off);  off += A((size_t)N0 * CAP2);
    size_t needA = pA + (size_t)N0 * D;  // pre2 words
    if (off < needA) off = needA;
    float* pre2 = ws + pA;

    // --- ELL payload block B: pay_d1, pay_d2 (dead after aggh d1/d2) ---
    // pre1 aliases this block (written by aggf, after both are dead).
    size_t pB = off;
    int* pay_d1 = (int*)(ws + off); off += A((size_t)N1 * CAP1);
    int* pay_d2 = (int*)(ws + off); off += A((size_t)N2 * CAP1);
    size_t needB = pB + (size_t)N0 * D;  // pre1 words
    if (off < needB) off = needB;
    float* pre1 = ws + pB;

    int* pay_s2 = (int*)(ws + off); off += A((size_t)N0 * CAP2);
    float* pre3 = out;  // d_out doubles as pre3 scratch

    // concatenated cursors [d1:N1][d2:N2][d12:N2][s1:N0][s2:N0] (zeroed)
    const int NT = N1 + 2 * N2 + 2 * N0;
    int* cur = (int*)(ws + off); off += A(NT);
    const int cb_d1 = 0, cb_d2 = N1, cb_d12 = N1 + N2;
    const int cb_s1 = N1 + 2 * N2, cb_s2 = N1 + 2 * N2 + N0;

    hipMemsetAsync((void*)cur, 0, (size_t)NT * sizeof(int), stream);

    // x_node -> fp16
    long n2 = (long)N0 * D / 2;
    f2h_kernel<<<(n2 + 255) / 256, 256, 0, stream>>>((const float2*)x_node,
                                                     (__half2*)xh, n2);

    // windowed ELL fills (cursor atomic doubles as histogram; no scan)
    FillJobs5 F;
    F.j[0] = {ei1_dst, ei1_src, ew1, pay_d1, cb_d1, CAP1, E1, N1};
    F.j[1] = {ei2_dst, ei2_src, ew2, pay_d2, cb_d2, CAP1, E2, N2};
    F.j[2] = {ei12_dst, ei12_src, nullptr, pay_d12, cb_d12, CAP2, E12, N2};
    F.j[3] = {ei1_src, ei1_dst, nullptr, pay_s1, cb_s1, CAP2, E1, N0};
    F.j[4] = {ei2_src, ei2_dst, ew2, pay_s2, cb_s2, CAP2, E2, N0};
    for (int k = 0; k < KPASS; ++k)
        fill_pass_kernel<<<dim3(2048, 5), 256, 0, stream>>>(F, k, cur);

    // aggregations
    auto blocks = [](int n) { return (n + 3) / 4; };
    aggh_kernel<true><<<blocks(N1), 256, 0, stream>>>(
        xh, D, cur + cb_d1, CAP1, pay_d1, x1, net1h, D, 0, N1);
    aggh_kernel<true><<<blocks(N2), 256, 0, stream>>>(
        xh, D, cur + cb_d2, CAP1, pay_d2, x2, combo, 2 * D, 0, N2);
    aggh_kernel<false><<<blocks(N2), 256, 0, stream>>>(
        net1h, D, cur + cb_d12, CAP2, pay_d12, x2, combo, 2 * D, D, N2);
    aggf_kernel<<<blocks(N0), 256, 0, stream>>>(net1h, cur + cb_s1, CAP2,
                                                pay_s1, pre1, N0);
    agg2_kernel<<<blocks(N0), 256, 0, stream>>>(combo, cur + cb_s2, CAP2,
                                                pay_s2, pre2, pre3, N0);

    // linear + relu (in place)
    const int gb = (N0 + 31) / 32;
    linrelu_kernel<<<gb, 256, 0, stream>>>(pre1, W1, b1, N0);
    linrelu_kernel<<<gb, 256, 0, stream>>>(pre2, W2, b2, N0);
    linrelu_kernel<<<gb, 256, 0, stream>>>(pre3, W12, b12, N0);

    // attention combine (p3 aliases out)
    attn_kernel<<<(N0 + 3) / 4, 256, 0, stream>>>(pre1, pre2, pre3, att, out, N0);
}